// Round 8
// baseline (228.151 us; speedup 1.0000x reference)
//
#include <hip/hip_runtime.h>
#include <math.h>

// ---------------------------------------------------------------------------
// MultiHeadAttention: B=8, S=1024, H=12, D=768, DH=64. fp32 in/out.
// R8: attention rebuilt on mfma_f32_32x32x16_bf16 with 4 waves x (32 qrows x
// full j/d) -> 40% fewer LDS-read cycles per FLOP (attn was measured ~89%
// LDS-pipe-bound). qkv: 256x128 tile @ 512 threads (2x work per barrier
// drain, latency-bound before). out/prep unchanged.
// ---------------------------------------------------------------------------

constexpr int NB  = 8;
constexpr int SEQ = 1024;
constexpr int NH  = 12;
constexpr int DM  = 768;
constexpr int DHD = 64;
constexpr int MROWS = NB * SEQ;      // 8192
constexpr int NQKV  = 3 * NH * DHD;  // 2304

typedef __attribute__((ext_vector_type(8))) short short8;
typedef __attribute__((ext_vector_type(4))) float f32x4;
typedef __attribute__((ext_vector_type(16))) float f32x16;

#define MFMA16(a,b,c) __builtin_amdgcn_mfma_f32_16x16x32_bf16((a),(b),(c),0,0,0)
#define MFMA32(a,b,c) __builtin_amdgcn_mfma_f32_32x32x16_bf16((a),(b),(c),0,0,0)

#if __has_builtin(__builtin_amdgcn_exp2f)
#define EXP2(x) __builtin_amdgcn_exp2f(x)
#else
#define EXP2(x) exp2f(x)
#endif

// RNE float->bf16
__device__ __forceinline__ unsigned short f2bf(float f) {
    unsigned u = __float_as_uint(f);
    return (unsigned short)((u + 0x7fffu + ((u >> 16) & 1u)) >> 16);
}
// round-half-up float->bf16 (2 VALU) — P in the attention hot loop
__device__ __forceinline__ unsigned short f2bf_fast(float f) {
    return (unsigned short)((__float_as_uint(f) + 0x8000u) >> 16);
}

// async 16B/lane global->LDS (LDS dest wave-uniform base + lane*16)
__device__ __forceinline__ void gl_lds16(const unsigned short* g, unsigned short* l) {
    __builtin_amdgcn_global_load_lds(
        (const __attribute__((address_space(1))) void*)g,
        (__attribute__((address_space(3))) void*)l, 16, 0, 0);
}

// 128B-row tiles ([rows][64] bf16), swizzle: chunk at pos (c+r)&7.
// One call stages rows [i*8, i*8+8) (1 KB).
__device__ __forceinline__ void stageK(unsigned short* lds, const unsigned short* gbase,
                                       int i, int ln, int ldg) {
    int r    = i * 8 + (ln >> 3);
    int cpos = ln & 7;
    int cdat = (cpos - r) & 7;
    gl_lds16(gbase + (size_t)r * ldg + cdat * 8, lds + i * 512);
}
__device__ __forceinline__ short8 ldK(const unsigned short* buf, int row, int chunk) {
    int c = (chunk + row) & 7;
    return *(const short8*)&buf[row * 64 + c * 8];
}

// ---------------------------------------------------------------------------
// Fused prep: blocks [0,6144) convert x fp32->bf16; blocks [6144,6720)
// transpose+convert Wq/Wk/Wv (per-head [768][64] -> [64][768]) and Wo.
// ---------------------------------------------------------------------------
__global__ __launch_bounds__(256) void prep_k(
    const float* __restrict__ x,
    const float* __restrict__ Wq, const float* __restrict__ Wk,
    const float* __restrict__ Wv, const float* __restrict__ Wo,
    unsigned short* __restrict__ xb, unsigned short* __restrict__ wt,
    unsigned short* __restrict__ wot) {
    __shared__ float tb[64][65];
    const int blk = blockIdx.x, tid = threadIdx.x;
    if (blk < 6144) {  // x conversion: 6144*256 float4 = elsX
        const int i = blk * 256 + tid;
        float4 v = ((const float4*)x)[i];
        ushort4 o;
        o.x = f2bf(v.x); o.y = f2bf(v.y); o.z = f2bf(v.z); o.w = f2bf(v.w);
        ((ushort4*)xb)[i] = o;
        return;
    }
    const int t = blk - 6144;       // 0..575
    const int job = t / 144, lb = t % 144;
    const float* W;
    unsigned short* dst;
    int C, r0, c0;
    if (job < 3) {
        const float* Ws = (job == 0) ? Wq : (job == 1 ? Wk : Wv);
        const int h = lb / 12, rb = lb % 12;
        W = Ws + (size_t)h * (DM * DHD);                // [768][64]
        dst = wt + (size_t)(job * 12 + h) * (DM * DHD); // rows = e, cols = d
        C = DHD; r0 = rb * 64; c0 = 0;
    } else {
        W = Wo; dst = wot; C = DM;
        r0 = (lb / 12) * 64; c0 = (lb % 12) * 64;
    }
    const int rr = tid >> 2, cc = (tid & 3) * 16;
#pragma unroll
    for (int j = 0; j < 16; j += 4) {
        float4 v = *(const float4*)&W[(size_t)(r0 + rr) * C + c0 + cc + j];
        tb[rr][cc + j + 0] = v.x;
        tb[rr][cc + j + 1] = v.y;
        tb[rr][cc + j + 2] = v.z;
        tb[rr][cc + j + 3] = v.w;
    }
    __syncthreads();
#pragma unroll
    for (int j = 0; j < 16; ++j)
        dst[(size_t)(c0 + rr) * DM + r0 + cc + j] = f2bf(tb[cc + j][rr]);
}

// ---------------------------------------------------------------------------
// Kernel 1: QKV projection. Tile 256x128, BK=64, single-buffered, 512 thr =
// 4x2 waves of 64x64. q/k transposed orientation (packed ushort4 epilogue);
// v normal (packed along seq into vT). Grid (32, 18).
// ---------------------------------------------------------------------------
__global__ __launch_bounds__(512, 4) void qkv_mfma_k(
    const unsigned short* __restrict__ xb, const unsigned short* __restrict__ wt,
    const float* __restrict__ bq, const float* __restrict__ bk, const float* __restrict__ bv,
    unsigned short* __restrict__ qb, unsigned short* __restrict__ kb,
    unsigned short* __restrict__ vT) {
    __shared__ unsigned short Ah[256 * 64], Bh[128 * 64];   // 32 KB + 16 KB

    const int tid = threadIdx.x;
    const int wv = tid >> 6, ln = tid & 63, quad = ln >> 4, lnid = ln & 15;
    const int wvm = wv >> 1, wvn = wv & 1;
    const int row0 = blockIdx.x * 256, col0 = blockIdx.y * 128;
    const int sel = (col0 >= 2 * DM) ? 2 : (col0 >= DM ? 1 : 0);

    f32x4 acc[4][4];
#pragma unroll
    for (int i = 0; i < 4; ++i)
#pragma unroll
        for (int j = 0; j < 4; ++j) acc[i][j] = (f32x4){0.f, 0.f, 0.f, 0.f};

    const unsigned short* Ahg = xb + (size_t)row0 * DM;
    const unsigned short* Bhg = wt + (size_t)col0 * DM;
    constexpr int NIT = DM / 64;  // 12

    if (sel < 2) {
        // ---- transposed: acc[et][st], D rows = e, cols = srow ----
        for (int it = 0; it < NIT; ++it) {
            const int kc = it * 64;
            __syncthreads();
#pragma unroll
            for (int c = 0; c < 4; ++c) stageK(Ah, Ahg + kc, wv * 4 + c, ln, DM);
#pragma unroll
            for (int c = 0; c < 2; ++c) stageK(Bh, Bhg + kc, wv * 2 + c, ln, DM);
            __syncthreads();
#pragma unroll
            for (int ks = 0; ks < 2; ++ks) {
                short8 a[4], b[4];
#pragma unroll
                for (int i = 0; i < 4; ++i)
                    a[i] = ldK(Ah, wvm * 64 + i * 16 + lnid, ks * 4 + quad);
#pragma unroll
                for (int j = 0; j < 4; ++j)
                    b[j] = ldK(Bh, wvn * 64 + j * 16 + lnid, ks * 4 + quad);
#pragma unroll
                for (int j = 0; j < 4; ++j)
#pragma unroll
                    for (int i = 0; i < 4; ++i)
                        acc[j][i] = MFMA16(b[j], a[i], acc[j][i]);
            }
        }
        // q prescale folds 1/sqrt(64) and log2(e) so softmax is bare exp2
        const float scale = (sel == 0) ? 0.18033688011112042f : 1.0f;
        const float* bias = (sel == 0) ? bq : bk;
        unsigned short* oh = (sel == 0) ? qb : kb;
#pragma unroll
        for (int et = 0; et < 4; ++et) {
            const int e = col0 + wvn * 64 + et * 16 + quad * 4;
            const int he = e - sel * DM;
            const int hh2 = he >> 6, ee = he & 63;
            float4 bs = *(const float4*)&bias[he];
#pragma unroll
            for (int st = 0; st < 4; ++st) {
                const int srow = row0 + wvm * 64 + st * 16 + lnid;
                const int bb = srow >> 10, ss = srow & (SEQ - 1);
                ushort4 pk;
                pk.x = f2bf((acc[et][st][0] + bs.x) * scale);
                pk.y = f2bf((acc[et][st][1] + bs.y) * scale);
                pk.z = f2bf((acc[et][st][2] + bs.z) * scale);
                pk.w = f2bf((acc[et][st][3] + bs.w) * scale);
                *(ushort4*)&oh[((size_t)(bb * NH + hh2) * SEQ + ss) * DHD + ee] = pk;
            }
        }
    } else {
        // ---- normal: acc[st][et], D rows = srow, cols = e; packed along s ----
        for (int it = 0; it < NIT; ++it) {
            const int kc = it * 64;
            __syncthreads();
#pragma unroll
            for (int c = 0; c < 4; ++c) stageK(Ah, Ahg + kc, wv * 4 + c, ln, DM);
#pragma unroll
            for (int c = 0; c < 2; ++c) stageK(Bh, Bhg + kc, wv * 2 + c, ln, DM);
            __syncthreads();
#pragma unroll
            for (int ks = 0; ks < 2; ++ks) {
                short8 a[4], b[4];
#pragma unroll
                for (int i = 0; i < 4; ++i)
                    a[i] = ldK(Ah, wvm * 64 + i * 16 + lnid, ks * 4 + quad);
#pragma unroll
                for (int j = 0; j < 4; ++j)
                    b[j] = ldK(Bh, wvn * 64 + j * 16 + lnid, ks * 4 + quad);
#pragma unroll
                for (int i = 0; i < 4; ++i)
#pragma unroll
                    for (int j = 0; j < 4; ++j)
                        acc[i][j] = MFMA16(a[i], b[j], acc[i][j]);
            }
        }
#pragma unroll
        for (int i = 0; i < 4; ++i) {
#pragma unroll
            for (int j = 0; j < 4; ++j) {
                const int col = col0 + wvn * 64 + j * 16 + lnid;
                const int he = col - 2 * DM;
                const int hh2 = he >> 6, ee = he & 63;
                const float bs = bv[he];
                const int srow = row0 + wvm * 64 + i * 16 + quad * 4;
                const int bb = srow >> 10, ss = srow & (SEQ - 1);
                ushort4 pk;
                pk.x = f2bf(acc[i][j][0] + bs);
                pk.y = f2bf(acc[i][j][1] + bs);
                pk.z = f2bf(acc[i][j][2] + bs);
                pk.w = f2bf(acc[i][j][3] + bs);
                *(ushort4*)&vT[((size_t)(bb * NH + hh2) * DHD + ee) * SEQ + ss] = pk;
            }
        }
    }
}

// ---------------------------------------------------------------------------
// Kernel 2: flash attention on 32x32x16 MFMA. 256 thr = 4 waves; wave owns 32
// q-rows: scores S^T (j=64 x q=32, 8 MFMA), exp2, P->LDS (wave-private rows),
// PV ctx^T (d=64 x q=32, 8 MFMA). Q-frags persistent in regs. K/V dbuf.
// Grid 768 1-D, bh = blk % 96 fastest (XCD-local KV). LDS 16+16+16 = 48 KB.
// Per wave-iter: 20 ds_read_b128 + 8 b64 writes for 524k FLOP (was 0.92,
// now 0.57 LDS-cyc/kFLOP — attn measured ~89% LDS-pipe-bound in R7).
// ---------------------------------------------------------------------------
__global__ __launch_bounds__(256, 3) void attn_mfma_k(
    const unsigned short* __restrict__ qb, const unsigned short* __restrict__ kb,
    const unsigned short* __restrict__ vT, unsigned short* __restrict__ ctb) {
    __shared__ unsigned short ksh[2][64 * 64], vsm[2][64 * 64];
    __shared__ unsigned short ps[128 * 64];   // XOR-8 swizzled, wave-private rows

    const int tid = threadIdx.x;
    const int wv = tid >> 6, ln = tid & 63;
    const int l32 = ln & 31, lh = ln >> 5;
    const int bhid = blockIdx.x % 96, qt = blockIdx.x / 96;
    const int b = bhid / NH, h = bhid % NH;
    const int q0 = qt * 128;
    const unsigned short* qhb = qb + (size_t)bhid * (SEQ * DHD);
    const unsigned short* khb = kb + (size_t)bhid * (SEQ * DHD);
    const unsigned short* vTb = vT + (size_t)bhid * (DHD * SEQ);

    const int qrow = wv * 32 + l32;   // block-local q-row (n-operand index)

    // persistent q fragments: B-operand, n=qrow, k = kci*16 + lh*8 + i
    short8 qf[4];
#pragma unroll
    for (int kci = 0; kci < 4; ++kci)
        qf[kci] = *(const short8*)(qhb + (size_t)(q0 + qrow) * DHD + kci * 16 + lh * 8);

    f32x16 ctx[2];   // [dt]: D rows = d (within 32), cols = qrow
    ctx[0] = (f32x16)(0.0f);
    ctx[1] = (f32x16)(0.0f);
    float lsum = 0.f;

    // prefetch tile 0 into buffer 0 (wave stages rows [wv*16, wv*16+16))
    stageK(ksh[0], khb, wv * 2, ln, DHD);
    stageK(ksh[0], khb, wv * 2 + 1, ln, DHD);
    stageK(vsm[0], vTb, wv * 2, ln, SEQ);
    stageK(vsm[0], vTb, wv * 2 + 1, ln, SEQ);

    for (int kt = 0; kt < SEQ / 64; ++kt) {
        const int cur = kt & 1;
        __syncthreads();   // buf[cur] ready; prev readers of buf[cur^1] done
        if (kt + 1 < SEQ / 64) {
            const unsigned short* kn = khb + (kt + 1) * 64 * DHD;
            const unsigned short* vn = vTb + (kt + 1) * 64;
            stageK(ksh[cur ^ 1], kn, wv * 2, ln, DHD);
            stageK(ksh[cur ^ 1], kn, wv * 2 + 1, ln, DHD);
            stageK(vsm[cur ^ 1], vn, wv * 2, ln, SEQ);
            stageK(vsm[cur ^ 1], vn, wv * 2 + 1, ln, SEQ);
        }

        // ---- scores S^T: sc[jt] = MFMA32(K-frag, q-frag); rows j, cols qrow
        f32x16 sc[2];
        sc[0] = (f32x16)(0.0f);
        sc[1] = (f32x16)(0.0f);
#pragma unroll
        for (int kci = 0; kci < 4; ++kci) {
#pragma unroll
            for (int jt = 0; jt < 2; ++jt) {
                short8 kf = ldK(ksh[cur], jt * 32 + l32, 2 * kci + lh);
                sc[jt] = MFMA32(kf, qf[kci], sc[jt]);
            }
        }

        // ---- p = 2^s; per-lane sums; swizzled b64 P-writes (wave-private) ----
        // lane's sc element (jt, reg): j = jt*32 + 8*(reg>>2) + 4*lh + (reg&3)
#pragma unroll
        for (int jt = 0; jt < 2; ++jt) {
#pragma unroll
            for (int rg = 0; rg < 4; ++rg) {
                float p0 = EXP2(sc[jt][rg * 4 + 0]);
                float p1 = EXP2(sc[jt][rg * 4 + 1]);
                float p2 = EXP2(sc[jt][rg * 4 + 2]);
                float p3 = EXP2(sc[jt][rg * 4 + 3]);
                lsum += (p0 + p1) + (p2 + p3);
                ushort4 pw;
                pw.x = f2bf_fast(p0);
                pw.y = f2bf_fast(p1);
                pw.z = f2bf_fast(p2);
                pw.w = f2bf_fast(p3);
                const int cdat = jt * 4 + rg;            // j-chunk = 8*cdat + 4*lh + r
                const int cpos = (cdat + qrow) & 7;
                *(ushort4*)&ps[qrow * 64 + cpos * 8 + lh * 4] = pw;
            }
        }

        // ---- PV: ctx^T += MFMA32(V^T-frag, P-frag) ----
#pragma unroll
        for (int jk = 0; jk < 4; ++jk) {
            short8 pf = ldK(ps, qrow, 2 * jk + lh);
#pragma unroll
            for (int dt = 0; dt < 2; ++dt) {
                short8 vf = ldK(vsm[cur], dt * 32 + l32, 2 * jk + lh);
                ctx[dt] = MFMA32(vf, pf, ctx[dt]);
            }
        }
    }

    // ---- row sum: lane covers half the j's (its lh partition); pair-reduce
    float s = lsum + __shfl_xor(lsum, 32, 64);
    const float inv = 1.0f / s;
    const int srow = b * SEQ + q0 + qrow;
    // ctx element (dt, reg): d = dt*32 + 8*(reg>>2) + 4*lh + (reg&3)
#pragma unroll
    for (int dt = 0; dt < 2; ++dt) {
#pragma unroll
        for (int rg = 0; rg < 4; ++rg) {
            ushort4 pk;
            pk.x = f2bf(ctx[dt][rg * 4 + 0] * inv);
            pk.y = f2bf(ctx[dt][rg * 4 + 1] * inv);
            pk.z = f2bf(ctx[dt][rg * 4 + 2] * inv);
            pk.w = f2bf(ctx[dt][rg * 4 + 3] * inv);
            const int d = dt * 32 + 8 * rg + 4 * lh;
            *(ushort4*)&ctb[(size_t)srow * DM + h * DHD + d] = pk;
        }
    }
}

// ---------------------------------------------------------------------------
// Kernel 3: output projection. Tile 128x64, BK=64, single-buffered,
// transposed orientation -> float4 stores. Grid (64, 12). UNCHANGED.
// ---------------------------------------------------------------------------
__global__ __launch_bounds__(256, 3) void out_mfma_k(
    const unsigned short* __restrict__ ctb, const unsigned short* __restrict__ wot,
    const float* __restrict__ bo, float* __restrict__ out) {
    __shared__ unsigned short Ah[128 * 64], Bh[64 * 64];   // 16 KB + 8 KB

    const int tid = threadIdx.x;
    const int wv = tid >> 6, ln = tid & 63, quad = ln >> 4, lnid = ln & 15;
    const int wvm = wv >> 1, wvn = wv & 1;
    const int row0 = blockIdx.x * 128, col0 = blockIdx.y * 64;

    f32x4 acc[2][4];   // [jt][it]: D rows = outcol, cols = srow
#pragma unroll
    for (int j = 0; j < 2; ++j)
#pragma unroll
        for (int i = 0; i < 4; ++i) acc[j][i] = (f32x4){0.f, 0.f, 0.f, 0.f};

    const unsigned short* Ahg = ctb + (size_t)row0 * DM;
    const unsigned short* Bhg = wot + (size_t)col0 * DM;

    constexpr int NIT = DM / 64;  // 12
    for (int it = 0; it < NIT; ++it) {
        const int kc = it * 64;
        __syncthreads();
#pragma unroll
        for (int c = 0; c < 4; ++c) stageK(Ah, Ahg + kc, wv * 4 + c, ln, DM);
#pragma unroll
        for (int c = 0; c < 2; ++c) stageK(Bh, Bhg + kc, wv * 2 + c, ln, DM);
        __syncthreads();
#pragma unroll
        for (int ks = 0; ks < 2; ++ks) {
            short8 a[4], b[2];
#pragma unroll
            for (int i = 0; i < 4; ++i)
                a[i] = ldK(Ah, wvm * 64 + i * 16 + lnid, ks * 4 + quad);
#pragma unroll
            for (int j = 0; j < 2; ++j)
                b[j] = ldK(Bh, wvn * 32 + j * 16 + lnid, ks * 4 + quad);
#pragma unroll
            for (int j = 0; j < 2; ++j)
#pragma unroll
                for (int i = 0; i < 4; ++i)
                    acc[j][i] = MFMA16(b[j], a[i], acc[j][i]);
        }
    }

#pragma unroll
    for (int jt = 0; jt < 2; ++jt) {
        const int colb = col0 + wvn * 32 + jt * 16 + quad * 4;
        float4 bs = *(const float4*)&bo[colb];
#pragma unroll
        for (int it = 0; it < 4; ++it) {
            const int srow = row0 + wvm * 64 + it * 16 + lnid;
            float4 o;
            o.x = acc[jt][it][0] + bs.x;
            o.y = acc[jt][it][1] + bs.y;
            o.z = acc[jt][it][2] + bs.z;
            o.w = acc[jt][it][3] + bs.w;
            *(float4*)&out[(size_t)srow * DM + colb] = o;
        }
    }
}

// ---------------------------------------------------------------------------
extern "C" void kernel_launch(void* const* d_in, const int* in_sizes, int n_in,
                              void* d_out, int out_size, void* d_ws, size_t ws_size,
                              hipStream_t stream) {
    const float* x  = (const float*)d_in[0];
    const float* Wq = (const float*)d_in[1];
    const float* Wk = (const float*)d_in[2];
    const float* Wv = (const float*)d_in[3];
    const float* bq = (const float*)d_in[4];
    const float* bk = (const float*)d_in[5];
    const float* bv = (const float*)d_in[6];
    const float* Wo = (const float*)d_in[7];
    const float* bo = (const float*)d_in[8];
    float* out = (float*)d_out;

    // workspace: xb | wt | wot | qb | kb | vT. ctb aliases xb (disjoint lifetime).
    char* w = (char*)d_ws;
    const size_t elsX = (size_t)MROWS * DM;          // 6,291,456
    const size_t elsQ = (size_t)NB * NH * SEQ * DHD; // 6,291,456
    unsigned short* xb  = (unsigned short*)w;
    unsigned short* ctb = xb;  // alias, disjoint lifetime
    size_t off = elsX * 2;
    unsigned short* wt  = (unsigned short*)(w + off); off += (size_t)NQKV * DM * 2;
    unsigned short* wot = (unsigned short*)(w + off); off += (size_t)DM * DM * 2;
    unsigned short* qbp = (unsigned short*)(w + off); off += elsQ * 2;
    unsigned short* kbp = (unsigned short*)(w + off); off += elsQ * 2;
    unsigned short* vTp = (unsigned short*)(w + off); off += elsQ * 2;

    prep_k<<<dim3(6144 + 576), 256, 0, stream>>>(x, Wq, Wk, Wv, Wo, xb, wt, wot);
    qkv_mfma_k<<<dim3(MROWS / 256, NQKV / 128), 512, 0, stream>>>(
        xb, wt, bq, bk, bv, qbp, kbp, vTp);
    attn_mfma_k<<<dim3(768), 256, 0, stream>>>(qbp, kbp, vTp, ctb);
    out_mfma_k<<<dim3(MROWS / 128, DM / 64), 256, 0, stream>>>(ctb, wot, bo, out);
}

// Round 9
// 194.189 us; speedup vs baseline: 1.1749x; 1.1749x over previous
//
#include <hip/hip_runtime.h>
#include <math.h>

// ---------------------------------------------------------------------------
// MultiHeadAttention: B=8, S=1024, H=12, D=768, DH=64. fp32 in/out.
// R9: qkv reverted to R7's 128x128/256-thr config (R8's 256x128 doubled HBM
// traffic: FETCH 26->53 MB, WRITE 37->85 MB -> 2 blocks/CU overflowed XCD L2).
// attn keeps the R8 mfma_32x32x16 structure (LDS-cyc/kFLOP 0.92 -> 0.57).
// ---------------------------------------------------------------------------

constexpr int NB  = 8;
constexpr int SEQ = 1024;
constexpr int NH  = 12;
constexpr int DM  = 768;
constexpr int DHD = 64;
constexpr int MROWS = NB * SEQ;      // 8192
constexpr int NQKV  = 3 * NH * DHD;  // 2304

typedef __attribute__((ext_vector_type(8))) short short8;
typedef __attribute__((ext_vector_type(4))) float f32x4;
typedef __attribute__((ext_vector_type(16))) float f32x16;

#define MFMA16(a,b,c) __builtin_amdgcn_mfma_f32_16x16x32_bf16((a),(b),(c),0,0,0)
#define MFMA32(a,b,c) __builtin_amdgcn_mfma_f32_32x32x16_bf16((a),(b),(c),0,0,0)

#if __has_builtin(__builtin_amdgcn_exp2f)
#define EXP2(x) __builtin_amdgcn_exp2f(x)
#else
#define EXP2(x) exp2f(x)
#endif

// RNE float->bf16
__device__ __forceinline__ unsigned short f2bf(float f) {
    unsigned u = __float_as_uint(f);
    return (unsigned short)((u + 0x7fffu + ((u >> 16) & 1u)) >> 16);
}
// round-half-up float->bf16 (2 VALU) — P in the attention hot loop
__device__ __forceinline__ unsigned short f2bf_fast(float f) {
    return (unsigned short)((__float_as_uint(f) + 0x8000u) >> 16);
}

// async 16B/lane global->LDS (LDS dest wave-uniform base + lane*16)
__device__ __forceinline__ void gl_lds16(const unsigned short* g, unsigned short* l) {
    __builtin_amdgcn_global_load_lds(
        (const __attribute__((address_space(1))) void*)g,
        (__attribute__((address_space(3))) void*)l, 16, 0, 0);
}

// 128B-row tiles ([rows][64] bf16), swizzle: chunk at pos (c+r)&7.
// One call stages rows [i*8, i*8+8) (1 KB).
__device__ __forceinline__ void stageK(unsigned short* lds, const unsigned short* gbase,
                                       int i, int ln, int ldg) {
    int r    = i * 8 + (ln >> 3);
    int cpos = ln & 7;
    int cdat = (cpos - r) & 7;
    gl_lds16(gbase + (size_t)r * ldg + cdat * 8, lds + i * 512);
}
__device__ __forceinline__ short8 ldK(const unsigned short* buf, int row, int chunk) {
    int c = (chunk + row) & 7;
    return *(const short8*)&buf[row * 64 + c * 8];
}

// ---------------------------------------------------------------------------
// Fused prep: blocks [0,6144) convert x fp32->bf16; blocks [6144,6720)
// transpose+convert Wq/Wk/Wv (per-head [768][64] -> [64][768]) and Wo.
// ---------------------------------------------------------------------------
__global__ __launch_bounds__(256) void prep_k(
    const float* __restrict__ x,
    const float* __restrict__ Wq, const float* __restrict__ Wk,
    const float* __restrict__ Wv, const float* __restrict__ Wo,
    unsigned short* __restrict__ xb, unsigned short* __restrict__ wt,
    unsigned short* __restrict__ wot) {
    __shared__ float tb[64][65];
    const int blk = blockIdx.x, tid = threadIdx.x;
    if (blk < 6144) {  // x conversion: 6144*256 float4 = elsX
        const int i = blk * 256 + tid;
        float4 v = ((const float4*)x)[i];
        ushort4 o;
        o.x = f2bf(v.x); o.y = f2bf(v.y); o.z = f2bf(v.z); o.w = f2bf(v.w);
        ((ushort4*)xb)[i] = o;
        return;
    }
    const int t = blk - 6144;       // 0..575
    const int job = t / 144, lb = t % 144;
    const float* W;
    unsigned short* dst;
    int C, r0, c0;
    if (job < 3) {
        const float* Ws = (job == 0) ? Wq : (job == 1 ? Wk : Wv);
        const int h = lb / 12, rb = lb % 12;
        W = Ws + (size_t)h * (DM * DHD);                // [768][64]
        dst = wt + (size_t)(job * 12 + h) * (DM * DHD); // rows = e, cols = d
        C = DHD; r0 = rb * 64; c0 = 0;
    } else {
        W = Wo; dst = wot; C = DM;
        r0 = (lb / 12) * 64; c0 = (lb % 12) * 64;
    }
    const int rr = tid >> 2, cc = (tid & 3) * 16;
#pragma unroll
    for (int j = 0; j < 16; j += 4) {
        float4 v = *(const float4*)&W[(size_t)(r0 + rr) * C + c0 + cc + j];
        tb[rr][cc + j + 0] = v.x;
        tb[rr][cc + j + 1] = v.y;
        tb[rr][cc + j + 2] = v.z;
        tb[rr][cc + j + 3] = v.w;
    }
    __syncthreads();
#pragma unroll
    for (int j = 0; j < 16; ++j)
        dst[(size_t)(c0 + rr) * DM + r0 + cc + j] = f2bf(tb[cc + j][rr]);
}

// ---------------------------------------------------------------------------
// Kernel 1: QKV projection. Tile 128x128, BK=64, single-buffered, 2x2 waves.
// q/k blocks transposed orientation (packed ushort4 epilogue); v normal
// (packed along seq into vT). Grid (64, 18). R7 config (verified 43 us).
// ---------------------------------------------------------------------------
__global__ __launch_bounds__(256, 3) void qkv_mfma_k(
    const unsigned short* __restrict__ xb, const unsigned short* __restrict__ wt,
    const float* __restrict__ bq, const float* __restrict__ bk, const float* __restrict__ bv,
    unsigned short* __restrict__ qb, unsigned short* __restrict__ kb,
    unsigned short* __restrict__ vT) {
    __shared__ unsigned short Ah[128 * 64], Bh[128 * 64];   // 16 KB + 16 KB

    const int tid = threadIdx.x;
    const int wv = tid >> 6, ln = tid & 63, quad = ln >> 4, lnid = ln & 15;
    const int wvm = wv >> 1, wvn = wv & 1;
    const int row0 = blockIdx.x * 128, col0 = blockIdx.y * 128;
    const int sel = (col0 >= 2 * DM) ? 2 : (col0 >= DM ? 1 : 0);

    f32x4 acc[4][4];
#pragma unroll
    for (int i = 0; i < 4; ++i)
#pragma unroll
        for (int j = 0; j < 4; ++j) acc[i][j] = (f32x4){0.f, 0.f, 0.f, 0.f};

    const unsigned short* Ahg = xb + (size_t)row0 * DM;
    const unsigned short* Bhg = wt + (size_t)col0 * DM;
    constexpr int NIT = DM / 64;  // 12

    if (sel < 2) {
        // ---- transposed: acc[et][st], D rows = e, cols = srow ----
        for (int it = 0; it < NIT; ++it) {
            const int kc = it * 64;
            __syncthreads();
#pragma unroll
            for (int c = 0; c < 4; ++c) {
                stageK(Ah, Ahg + kc, wv * 4 + c, ln, DM);
                stageK(Bh, Bhg + kc, wv * 4 + c, ln, DM);
            }
            __syncthreads();
#pragma unroll
            for (int ks = 0; ks < 2; ++ks) {
                short8 a[4], b[4];
#pragma unroll
                for (int i = 0; i < 4; ++i)
                    a[i] = ldK(Ah, wvm * 64 + i * 16 + lnid, ks * 4 + quad);
#pragma unroll
                for (int j = 0; j < 4; ++j)
                    b[j] = ldK(Bh, wvn * 64 + j * 16 + lnid, ks * 4 + quad);
#pragma unroll
                for (int j = 0; j < 4; ++j)
#pragma unroll
                    for (int i = 0; i < 4; ++i)
                        acc[j][i] = MFMA16(b[j], a[i], acc[j][i]);
            }
        }
        // q prescale folds 1/sqrt(64) and log2(e) so softmax is bare exp2
        const float scale = (sel == 0) ? 0.18033688011112042f : 1.0f;
        const float* bias = (sel == 0) ? bq : bk;
        unsigned short* oh = (sel == 0) ? qb : kb;
#pragma unroll
        for (int et = 0; et < 4; ++et) {
            const int e = col0 + wvn * 64 + et * 16 + quad * 4;
            const int he = e - sel * DM;
            const int hh2 = he >> 6, ee = he & 63;
            float4 bs = *(const float4*)&bias[he];
#pragma unroll
            for (int st = 0; st < 4; ++st) {
                const int srow = row0 + wvm * 64 + st * 16 + lnid;
                const int bb = srow >> 10, ss = srow & (SEQ - 1);
                ushort4 pk;
                pk.x = f2bf((acc[et][st][0] + bs.x) * scale);
                pk.y = f2bf((acc[et][st][1] + bs.y) * scale);
                pk.z = f2bf((acc[et][st][2] + bs.z) * scale);
                pk.w = f2bf((acc[et][st][3] + bs.w) * scale);
                *(ushort4*)&oh[((size_t)(bb * NH + hh2) * SEQ + ss) * DHD + ee] = pk;
            }
        }
    } else {
        // ---- normal: acc[st][et], D rows = srow, cols = e; packed along s ----
        for (int it = 0; it < NIT; ++it) {
            const int kc = it * 64;
            __syncthreads();
#pragma unroll
            for (int c = 0; c < 4; ++c) {
                stageK(Ah, Ahg + kc, wv * 4 + c, ln, DM);
                stageK(Bh, Bhg + kc, wv * 4 + c, ln, DM);
            }
            __syncthreads();
#pragma unroll
            for (int ks = 0; ks < 2; ++ks) {
                short8 a[4], b[4];
#pragma unroll
                for (int i = 0; i < 4; ++i)
                    a[i] = ldK(Ah, wvm * 64 + i * 16 + lnid, ks * 4 + quad);
#pragma unroll
                for (int j = 0; j < 4; ++j)
                    b[j] = ldK(Bh, wvn * 64 + j * 16 + lnid, ks * 4 + quad);
#pragma unroll
                for (int i = 0; i < 4; ++i)
#pragma unroll
                    for (int j = 0; j < 4; ++j)
                        acc[i][j] = MFMA16(a[i], b[j], acc[i][j]);
            }
        }
#pragma unroll
        for (int i = 0; i < 4; ++i) {
#pragma unroll
            for (int j = 0; j < 4; ++j) {
                const int col = col0 + wvn * 64 + j * 16 + lnid;
                const int he = col - 2 * DM;
                const int hh2 = he >> 6, ee = he & 63;
                const float bs = bv[he];
                const int srow = row0 + wvm * 64 + i * 16 + quad * 4;
                const int bb = srow >> 10, ss = srow & (SEQ - 1);
                ushort4 pk;
                pk.x = f2bf(acc[i][j][0] + bs);
                pk.y = f2bf(acc[i][j][1] + bs);
                pk.z = f2bf(acc[i][j][2] + bs);
                pk.w = f2bf(acc[i][j][3] + bs);
                *(ushort4*)&vT[((size_t)(bb * NH + hh2) * DHD + ee) * SEQ + ss] = pk;
            }
        }
    }
}

// ---------------------------------------------------------------------------
// Kernel 2: flash attention on 32x32x16 MFMA. 256 thr = 4 waves; wave owns 32
// q-rows: scores S^T (j=64 x q=32, 8 MFMA), exp2, P->LDS (wave-private rows),
// PV ctx^T (d=64 x q=32, 8 MFMA). Q-frags persistent in regs. K/V dbuf.
// Grid 768 1-D, bh = blk % 96 fastest (XCD-local KV). LDS 16+16+16 = 48 KB.
// ---------------------------------------------------------------------------
__global__ __launch_bounds__(256, 3) void attn_mfma_k(
    const unsigned short* __restrict__ qb, const unsigned short* __restrict__ kb,
    const unsigned short* __restrict__ vT, unsigned short* __restrict__ ctb) {
    __shared__ unsigned short ksh[2][64 * 64], vsm[2][64 * 64];
    __shared__ unsigned short ps[128 * 64];   // XOR-8 swizzled, wave-private rows

    const int tid = threadIdx.x;
    const int wv = tid >> 6, ln = tid & 63;
    const int l32 = ln & 31, lh = ln >> 5;
    const int bhid = blockIdx.x % 96, qt = blockIdx.x / 96;
    const int b = bhid / NH, h = bhid % NH;
    const int q0 = qt * 128;
    const unsigned short* qhb = qb + (size_t)bhid * (SEQ * DHD);
    const unsigned short* khb = kb + (size_t)bhid * (SEQ * DHD);
    const unsigned short* vTb = vT + (size_t)bhid * (DHD * SEQ);

    const int qrow = wv * 32 + l32;   // block-local q-row (n-operand index)

    // persistent q fragments: B-operand, n=qrow, k = kci*16 + lh*8 + i
    short8 qf[4];
#pragma unroll
    for (int kci = 0; kci < 4; ++kci)
        qf[kci] = *(const short8*)(qhb + (size_t)(q0 + qrow) * DHD + kci * 16 + lh * 8);

    f32x16 ctx[2];   // [dt]: D rows = d (within 32), cols = qrow
    ctx[0] = (f32x16)(0.0f);
    ctx[1] = (f32x16)(0.0f);
    float lsum = 0.f;

    // prefetch tile 0 into buffer 0 (wave stages rows [wv*16, wv*16+16))
    stageK(ksh[0], khb, wv * 2, ln, DHD);
    stageK(ksh[0], khb, wv * 2 + 1, ln, DHD);
    stageK(vsm[0], vTb, wv * 2, ln, SEQ);
    stageK(vsm[0], vTb, wv * 2 + 1, ln, SEQ);

    for (int kt = 0; kt < SEQ / 64; ++kt) {
        const int cur = kt & 1;
        __syncthreads();   // buf[cur] ready; prev readers of buf[cur^1] done
        if (kt + 1 < SEQ / 64) {
            const unsigned short* kn = khb + (kt + 1) * 64 * DHD;
            const unsigned short* vn = vTb + (kt + 1) * 64;
            stageK(ksh[cur ^ 1], kn, wv * 2, ln, DHD);
            stageK(ksh[cur ^ 1], kn, wv * 2 + 1, ln, DHD);
            stageK(vsm[cur ^ 1], vn, wv * 2, ln, SEQ);
            stageK(vsm[cur ^ 1], vn, wv * 2 + 1, ln, SEQ);
        }

        // ---- scores S^T: sc[jt] = MFMA32(K-frag, q-frag); rows j, cols qrow
        f32x16 sc[2];
        sc[0] = (f32x16)(0.0f);
        sc[1] = (f32x16)(0.0f);
#pragma unroll
        for (int kci = 0; kci < 4; ++kci) {
#pragma unroll
            for (int jt = 0; jt < 2; ++jt) {
                short8 kf = ldK(ksh[cur], jt * 32 + l32, 2 * kci + lh);
                sc[jt] = MFMA32(kf, qf[kci], sc[jt]);
            }
        }

        // ---- p = 2^s; per-lane sums; swizzled b64 P-writes (wave-private) ----
        // lane's sc element (jt, reg): j = jt*32 + 8*(reg>>2) + 4*lh + (reg&3)
#pragma unroll
        for (int jt = 0; jt < 2; ++jt) {
#pragma unroll
            for (int rg = 0; rg < 4; ++rg) {
                float p0 = EXP2(sc[jt][rg * 4 + 0]);
                float p1 = EXP2(sc[jt][rg * 4 + 1]);
                float p2 = EXP2(sc[jt][rg * 4 + 2]);
                float p3 = EXP2(sc[jt][rg * 4 + 3]);
                lsum += (p0 + p1) + (p2 + p3);
                ushort4 pw;
                pw.x = f2bf_fast(p0);
                pw.y = f2bf_fast(p1);
                pw.z = f2bf_fast(p2);
                pw.w = f2bf_fast(p3);
                const int cdat = jt * 4 + rg;            // j-chunk = 8*cdat + 4*lh + r
                const int cpos = (cdat + qrow) & 7;
                *(ushort4*)&ps[qrow * 64 + cpos * 8 + lh * 4] = pw;
            }
        }

        // ---- PV: ctx^T += MFMA32(V^T-frag, P-frag) ----
#pragma unroll
        for (int jk = 0; jk < 4; ++jk) {
            short8 pf = ldK(ps, qrow, 2 * jk + lh);
#pragma unroll
            for (int dt = 0; dt < 2; ++dt) {
                short8 vf = ldK(vsm[cur], dt * 32 + l32, 2 * jk + lh);
                ctx[dt] = MFMA32(vf, pf, ctx[dt]);
            }
        }
    }

    // ---- row sum: lane covers half the j's (its lh partition); pair-reduce
    float s = lsum + __shfl_xor(lsum, 32, 64);
    const float inv = 1.0f / s;
    const int srow = b * SEQ + q0 + qrow;
    // ctx element (dt, reg): d = dt*32 + 8*(reg>>2) + 4*lh + (reg&3)
#pragma unroll
    for (int dt = 0; dt < 2; ++dt) {
#pragma unroll
        for (int rg = 0; rg < 4; ++rg) {
            ushort4 pk;
            pk.x = f2bf(ctx[dt][rg * 4 + 0] * inv);
            pk.y = f2bf(ctx[dt][rg * 4 + 1] * inv);
            pk.z = f2bf(ctx[dt][rg * 4 + 2] * inv);
            pk.w = f2bf(ctx[dt][rg * 4 + 3] * inv);
            const int d = dt * 32 + 8 * rg + 4 * lh;
            *(ushort4*)&ctb[(size_t)srow * DM + h * DHD + d] = pk;
        }
    }
}

// ---------------------------------------------------------------------------
// Kernel 3: output projection. Tile 128x64, BK=64, single-buffered,
// transposed orientation -> float4 stores. Grid (64, 12). UNCHANGED.
// ---------------------------------------------------------------------------
__global__ __launch_bounds__(256, 3) void out_mfma_k(
    const unsigned short* __restrict__ ctb, const unsigned short* __restrict__ wot,
    const float* __restrict__ bo, float* __restrict__ out) {
    __shared__ unsigned short Ah[128 * 64], Bh[64 * 64];   // 16 KB + 8 KB

    const int tid = threadIdx.x;
    const int wv = tid >> 6, ln = tid & 63, quad = ln >> 4, lnid = ln & 15;
    const int wvm = wv >> 1, wvn = wv & 1;
    const int row0 = blockIdx.x * 128, col0 = blockIdx.y * 64;

    f32x4 acc[2][4];   // [jt][it]: D rows = outcol, cols = srow
#pragma unroll
    for (int j = 0; j < 2; ++j)
#pragma unroll
        for (int i = 0; i < 4; ++i) acc[j][i] = (f32x4){0.f, 0.f, 0.f, 0.f};

    const unsigned short* Ahg = ctb + (size_t)row0 * DM;
    const unsigned short* Bhg = wot + (size_t)col0 * DM;

    constexpr int NIT = DM / 64;  // 12
    for (int it = 0; it < NIT; ++it) {
        const int kc = it * 64;
        __syncthreads();
#pragma unroll
        for (int c = 0; c < 4; ++c) stageK(Ah, Ahg + kc, wv * 4 + c, ln, DM);
#pragma unroll
        for (int c = 0; c < 2; ++c) stageK(Bh, Bhg + kc, wv * 2 + c, ln, DM);
        __syncthreads();
#pragma unroll
        for (int ks = 0; ks < 2; ++ks) {
            short8 a[4], b[2];
#pragma unroll
            for (int i = 0; i < 4; ++i)
                a[i] = ldK(Ah, wvm * 64 + i * 16 + lnid, ks * 4 + quad);
#pragma unroll
            for (int j = 0; j < 2; ++j)
                b[j] = ldK(Bh, wvn * 32 + j * 16 + lnid, ks * 4 + quad);
#pragma unroll
            for (int j = 0; j < 2; ++j)
#pragma unroll
                for (int i = 0; i < 4; ++i)
                    acc[j][i] = MFMA16(b[j], a[i], acc[j][i]);
        }
    }

#pragma unroll
    for (int jt = 0; jt < 2; ++jt) {
        const int colb = col0 + wvn * 32 + jt * 16 + quad * 4;
        float4 bs = *(const float4*)&bo[colb];
#pragma unroll
        for (int it = 0; it < 4; ++it) {
            const int srow = row0 + wvm * 64 + it * 16 + lnid;
            float4 o;
            o.x = acc[jt][it][0] + bs.x;
            o.y = acc[jt][it][1] + bs.y;
            o.z = acc[jt][it][2] + bs.z;
            o.w = acc[jt][it][3] + bs.w;
            *(float4*)&out[(size_t)srow * DM + colb] = o;
        }
    }
}

// ---------------------------------------------------------------------------
extern "C" void kernel_launch(void* const* d_in, const int* in_sizes, int n_in,
                              void* d_out, int out_size, void* d_ws, size_t ws_size,
                              hipStream_t stream) {
    const float* x  = (const float*)d_in[0];
    const float* Wq = (const float*)d_in[1];
    const float* Wk = (const float*)d_in[2];
    const float* Wv = (const float*)d_in[3];
    const float* bq = (const float*)d_in[4];
    const float* bk = (const float*)d_in[5];
    const float* bv = (const float*)d_in[6];
    const float* Wo = (const float*)d_in[7];
    const float* bo = (const float*)d_in[8];
    float* out = (float*)d_out;

    // workspace: xb | wt | wot | qb | kb | vT. ctb aliases xb (disjoint lifetime).
    char* w = (char*)d_ws;
    const size_t elsX = (size_t)MROWS * DM;          // 6,291,456
    const size_t elsQ = (size_t)NB * NH * SEQ * DHD; // 6,291,456
    unsigned short* xb  = (unsigned short*)w;
    unsigned short* ctb = xb;  // alias, disjoint lifetime
    size_t off = elsX * 2;
    unsigned short* wt  = (unsigned short*)(w + off); off += (size_t)NQKV * DM * 2;
    unsigned short* wot = (unsigned short*)(w + off); off += (size_t)DM * DM * 2;
    unsigned short* qbp = (unsigned short*)(w + off); off += elsQ * 2;
    unsigned short* kbp = (unsigned short*)(w + off); off += elsQ * 2;
    unsigned short* vTp = (unsigned short*)(w + off); off += elsQ * 2;

    prep_k<<<dim3(6144 + 576), 256, 0, stream>>>(x, Wq, Wk, Wv, Wo, xb, wt, wot);
    qkv_mfma_k<<<dim3(MROWS / 128, NQKV / 128), 256, 0, stream>>>(
        xb, wt, bq, bk, bv, qbp, kbp, vTp);
    attn_mfma_k<<<dim3(768), 256, 0, stream>>>(qbp, kbp, vTp, ctb);
    out_mfma_k<<<dim3(MROWS / 128, DM / 64), 256, 0, stream>>>(ctb, wot, bo, out);
}